// Round 2
// baseline (2644.585 us; speedup 1.0000x reference)
//
#include <hip/hip_runtime.h>

// GraphSAGE fused pipeline, fp32 baseline.
// All matmuls are C = A @ W^T with W row-major (N,K) -- "gemm_bt" shape.
// Generic kernel: K-tiled (KT=32); W tile staged TRANSPOSED in LDS
// (Wlds[k][n], pad +1) so thread->column reads are stride-1 (2-way aliasing,
// free on gfx950); A tile reads are wave-uniform broadcasts (ds_read_b128).
// Each thread owns CPT columns x RPB rows of accumulator.
// Optional fused epilogue: relu -> *mask[row] -> max over SPOOL-row groups.

template<int NCOLS, int CPT, int RPB, int SPOOL>
__global__ __launch_bounds__(NCOLS / CPT) void gemm_bt(
    const float* __restrict__ A, const float* __restrict__ W,
    const float* __restrict__ mask, float* __restrict__ Cout,
    int K, int ldc, int col_off)
{
    constexpr int KT = 32;
    constexpr int NT = NCOLS / CPT;           // threads per block
    __shared__ __align__(16) float Wlds[KT][NCOLS + 1];
    __shared__ __align__(16) float Alds[RPB][KT];

    const int t = threadIdx.x;
    const long row0 = (long)blockIdx.x * RPB;
    const float* __restrict__ Arow = A + row0 * K;

    float acc[CPT][RPB];
#pragma unroll
    for (int c = 0; c < CPT; ++c)
#pragma unroll
        for (int r = 0; r < RPB; ++r) acc[c][r] = 0.f;

    for (int kt = 0; kt < K; kt += KT) {
        // ---- stage W tile transposed: Wlds[kk][n] = W[n][kt+kk] ----
        {
            constexpr int F4 = NCOLS * (KT / 4);
            for (int i = t; i < F4; i += NT) {
                const int n  = i / (KT / 4);
                const int k4 = (i % (KT / 4)) * 4;
                const float4 v = *(const float4*)&W[(long)n * K + kt + k4];
                Wlds[k4 + 0][n] = v.x;
                Wlds[k4 + 1][n] = v.y;
                Wlds[k4 + 2][n] = v.z;
                Wlds[k4 + 3][n] = v.w;
            }
        }
        // ---- stage A tile: Alds[r][kk] = A[row0+r][kt+kk] ----
        {
            constexpr int F4 = RPB * (KT / 4);
            for (int i = t; i < F4; i += NT) {
                const int r  = i / (KT / 4);
                const int k4 = (i % (KT / 4)) * 4;
                *(float4*)&Alds[r][k4] = *(const float4*)&Arow[(long)r * K + kt + k4];
            }
        }
        __syncthreads();

#pragma unroll
        for (int kk = 0; kk < KT; kk += 4) {
            float w[CPT][4];
#pragma unroll
            for (int c = 0; c < CPT; ++c) {
                const int d = t + c * NT;
                w[c][0] = Wlds[kk + 0][d];
                w[c][1] = Wlds[kk + 1][d];
                w[c][2] = Wlds[kk + 2][d];
                w[c][3] = Wlds[kk + 3][d];
            }
#pragma unroll
            for (int r = 0; r < RPB; ++r) {
                const float4 a = *(const float4*)&Alds[r][kk];   // broadcast
#pragma unroll
                for (int c = 0; c < CPT; ++c) {
                    acc[c][r] = fmaf(a.x, w[c][0], acc[c][r]);
                    acc[c][r] = fmaf(a.y, w[c][1], acc[c][r]);
                    acc[c][r] = fmaf(a.z, w[c][2], acc[c][r]);
                    acc[c][r] = fmaf(a.w, w[c][3], acc[c][r]);
                }
            }
        }
        __syncthreads();
    }

    // ---- epilogue ----
    if constexpr (SPOOL > 0) {
        // relu -> *mask -> max over groups of SPOOL rows
#pragma unroll
        for (int g = 0; g < RPB / SPOOL; ++g) {
            float mv[SPOOL];
#pragma unroll
            for (int s = 0; s < SPOOL; ++s) mv[s] = mask[row0 + g * SPOOL + s];
#pragma unroll
            for (int c = 0; c < CPT; ++c) {
                const int d = t + c * NT;
                float m = 0.f;
#pragma unroll
                for (int s = 0; s < SPOOL; ++s) {
                    float v = acc[c][g * SPOOL + s];
                    v = v > 0.f ? v : 0.f;
                    v *= mv[s];
                    m = fmaxf(m, v);
                }
                const long orow = row0 / SPOOL + g;
                Cout[orow * ldc + col_off + d] = m;
            }
        }
    } else {
#pragma unroll
        for (int c = 0; c < CPT; ++c) {
            const int d = t + c * NT;
#pragma unroll
            for (int r = 0; r < RPB; ++r)
                Cout[(row0 + r) * ldc + col_off + d] = acc[c][r];
        }
    }
}

extern "C" void kernel_launch(void* const* d_in, const int* in_sizes, int n_in,
                              void* d_out, int out_size, void* d_ws, size_t ws_size,
                              hipStream_t stream) {
    const float* h0    = (const float*)d_in[0];   // (1024, 1, 256)
    const float* h1    = (const float*)d_in[1];   // (1024, 10, 256)
    const float* h2    = (const float*)d_in[2];   // (1024, 250, 256)
    const float* mask0 = (const float*)d_in[3];   // (1024, 1, 10, 1)  -> 10240 rows
    const float* mask1 = (const float*)d_in[4];   // (1024, 10, 25, 1) -> 256000 rows
    const float* Ws0   = (const float*)d_in[5];   // (256, 256)
    const float* Wn0   = (const float*)d_in[6];   // (256, 256)
    const float* Wp0   = (const float*)d_in[7];   // (256, 256)
    const float* Ws1   = (const float*)d_in[8];   // (256, 512)
    const float* Wn1   = (const float*)d_in[9];   // (256, 512)
    const float* Wp1   = (const float*)d_in[10];  // (256, 256)
    const float* Wout  = (const float*)d_in[11];  // (128, 512)
    float* out = (float*)d_out;                   // (1024, 128)

    float* ws = (float*)d_ws;
    float* pooled1  = ws;                          // (10240, 256)
    float* states1  = pooled1  + 10240L * 256;     // (10240, 512)
    float* pooled0  = states1  + 10240L * 512;     // (1024, 256)
    float* states0  = pooled0  + 1024L * 256;      // (1024, 512)
    float* pooled1b = states0  + 1024L * 512;      // (1024, 256)
    float* states0b = pooled1b + 1024L * 256;      // (1024, 512)

    const dim3 blk(128);

    // Layer0 j=1 neighbor: pooled1 = maxpool25(relu(h2 @ Wn0^T) * mask1)  [dominant]
    hipLaunchKernelGGL((gemm_bt<256, 2, 25, 25>), dim3(10240), blk, 0, stream,
                       h2, Wn0, mask1, pooled1, 256, 256, 0);
    // Layer0 j=0 neighbor: pooled0 = maxpool10(relu(h1 @ Wn0^T) * mask0)
    hipLaunchKernelGGL((gemm_bt<256, 2, 20, 10>), dim3(512), blk, 0, stream,
                       h1, Wn0, mask0, pooled0, 256, 256, 0);
    // states1[:, 0:256] = h1 @ Ws0^T
    hipLaunchKernelGGL((gemm_bt<256, 2, 16, 0>), dim3(640), blk, 0, stream,
                       h1, Ws0, nullptr, states1, 256, 512, 0);
    // states1[:, 256:512] = pooled1 @ Wp0^T
    hipLaunchKernelGGL((gemm_bt<256, 2, 16, 0>), dim3(640), blk, 0, stream,
                       pooled1, Wp0, nullptr, states1, 256, 512, 256);
    // states0[:, 0:256] = h0 @ Ws0^T
    hipLaunchKernelGGL((gemm_bt<256, 2, 16, 0>), dim3(64), blk, 0, stream,
                       h0, Ws0, nullptr, states0, 256, 512, 0);
    // states0[:, 256:512] = pooled0 @ Wp0^T
    hipLaunchKernelGGL((gemm_bt<256, 2, 16, 0>), dim3(64), blk, 0, stream,
                       pooled0, Wp0, nullptr, states0, 256, 512, 256);
    // Layer1 neighbor: pooled1b = maxpool10(relu(states1 @ Wn1^T) * mask0), K=512
    hipLaunchKernelGGL((gemm_bt<256, 2, 20, 10>), dim3(512), blk, 0, stream,
                       states1, Wn1, mask0, pooled1b, 512, 256, 0);
    // states0b[:, 0:256] = states0 @ Ws1^T, K=512
    hipLaunchKernelGGL((gemm_bt<256, 2, 16, 0>), dim3(64), blk, 0, stream,
                       states0, Ws1, nullptr, states0b, 512, 512, 0);
    // states0b[:, 256:512] = pooled1b @ Wp1^T, K=256
    hipLaunchKernelGGL((gemm_bt<256, 2, 16, 0>), dim3(64), blk, 0, stream,
                       pooled1b, Wp1, nullptr, states0b, 256, 512, 256);
    // out = states0b @ Wout^T, K=512, N=128
    hipLaunchKernelGGL((gemm_bt<128, 1, 16, 0>), dim3(64), blk, 0, stream,
                       states0b, Wout, nullptr, out, 512, 128, 0);
}

// Round 3
// 787.473 us; speedup vs baseline: 3.3583x; 3.3583x over previous
//
#include <hip/hip_runtime.h>
#include <hip/hip_bf16.h>

// GraphSAGE fused pipeline, bf16-MFMA version.
// All matmuls are C = A @ W^T (W row-major (N,K), f32 inputs).
// MFMA: v_mfma_f32_16x16x32_bf16. Verified layouts (learn_hip m89/m120):
//   A-frag: lane holds A[m=lane&15][k=(lane>>4)*8 + j], j=0..7 contiguous
//   B-frag: lane holds B'[n=lane&15][k=(lane>>4)*8 + j]  (B' = W, gemm-bt)
//   C/D   : col=lane&15, row=(lane>>4)*4 + reg
// LDS staged fragment-major: [tile][kgroup(4)][row(16)][8 elems] so each
// fragment is one aligned ds_read_b128; lane stride 16 B -> 2-way bank
// aliasing only (free on gfx950, m136).
// Pool kernels: block owns P parents padded to PR rows (PR=32 for S=25,
// PR=16 for S=10); relu*mask*max pooled in registers + shfl_xor across quads.

typedef __bf16 bf16_t;
typedef bf16_t bf16x8 __attribute__((ext_vector_type(8)));
typedef float  f32x4  __attribute__((ext_vector_type(4)));

template<typename AT>
__device__ inline bf16x8 load8_cvt(const AT* __restrict__ src) {
  if constexpr (sizeof(AT) == 4) {          // f32 source -> convert
    const float4 v0 = *(const float4*)src;
    const float4 v1 = *(const float4*)(src + 4);
    bf16x8 t;
    t[0]=(bf16_t)v0.x; t[1]=(bf16_t)v0.y; t[2]=(bf16_t)v0.z; t[3]=(bf16_t)v0.w;
    t[4]=(bf16_t)v1.x; t[5]=(bf16_t)v1.y; t[6]=(bf16_t)v1.z; t[7]=(bf16_t)v1.w;
    return t;
  } else {                                  // bf16 source -> straight 16B
    return *(const bf16x8*)src;
  }
}

// ---------------- pooled GEMM: out[p][0:256] = max_{s<S} relu(A[p*S+s]@W^T)*mask ----------------
template<int S, int PR, int P, typename AT>
__global__ __launch_bounds__(256) void pool_mfma(
    const AT* __restrict__ A, const float* __restrict__ W,
    const float* __restrict__ mask, bf16_t* __restrict__ out, int K)
{
  constexpr int ROWS = P * PR;              // 128 child rows (padded)
  constexpr int PM   = ROWS / 16;           // 8 m-tiles
  constexpr int MTP  = PR / 16;             // m-tiles per parent
  __shared__ bf16x8 Alds[PM * 4 * 16];      // 8 KB
  __shared__ bf16x8 Blds[16 * 4 * 16];      // 16 KB (N=256)
  __shared__ float  mlds[P * PR];

  const int tid  = threadIdx.x;
  const int lane = tid & 63;
  const int wv   = tid >> 6;
  const int quad = lane >> 4;
  const int lrow = lane & 15;
  const long p0  = (long)blockIdx.x * P;

  if (tid < P * S) mlds[(tid / S) * PR + (tid % S)] = mask[p0 * S + tid];

  f32x4 acc[PM][4];
#pragma unroll
  for (int pm = 0; pm < PM; ++pm)
#pragma unroll
    for (int nl = 0; nl < 4; ++nl) acc[pm][nl] = (f32x4){0.f, 0.f, 0.f, 0.f};

  for (int kt = 0; kt < K; kt += 32) {
    __syncthreads();
    // stage B (W): 256 rows x 32 k
    for (int i = tid; i < 256 * 4; i += 256) {
      const int n = i >> 2, kg = i & 3;
      Blds[((n >> 4) * 4 + kg) * 16 + (n & 15)] =
          load8_cvt(W + (long)n * K + kt + kg * 8);
    }
    // stage A: P parents x PR padded rows x 32 k
    for (int i = tid; i < ROWS * 4; i += 256) {
      const int mr = i >> 2, kg = i & 3;
      const int p = mr / PR, r = mr % PR;
      const long g = (p0 + p) * S + (r < S ? r : S - 1);   // clamp pad rows
      Alds[((mr >> 4) * 4 + kg) * 16 + (mr & 15)] =
          load8_cvt(A + g * (long)K + kt + kg * 8);
    }
    __syncthreads();

    bf16x8 bfr[4];
#pragma unroll
    for (int nl = 0; nl < 4; ++nl)
      bfr[nl] = Blds[((wv * 4 + nl) * 4 + quad) * 16 + lrow];
#pragma unroll
    for (int pm = 0; pm < PM; ++pm) {
      const bf16x8 afr = Alds[(pm * 4 + quad) * 16 + lrow];
#pragma unroll
      for (int nl = 0; nl < 4; ++nl)
        acc[pm][nl] = __builtin_amdgcn_mfma_f32_16x16x32_bf16(
            afr, bfr[nl], acc[pm][nl], 0, 0, 0);
    }
  }

  // epilogue: relu -> *mask -> max over S rows per parent
#pragma unroll
  for (int p = 0; p < P; ++p) {
#pragma unroll
    for (int nl = 0; nl < 4; ++nl) {
      float m = 0.f;
#pragma unroll
      for (int mt = 0; mt < MTP; ++mt) {
        const f32x4 v = acc[p * MTP + mt][nl];
#pragma unroll
        for (int reg = 0; reg < 4; ++reg) {
          const int row = mt * 16 + quad * 4 + reg;
          if (row < S)
            m = fmaxf(m, fmaxf(v[reg], 0.f) * mlds[p * PR + row]);
        }
      }
      m = fmaxf(m, __shfl_xor(m, 16));
      m = fmaxf(m, __shfl_xor(m, 32));
      if (lane < 16)
        out[(p0 + p) * 256 + wv * 64 + nl * 16 + lrow] = (bf16_t)m;
    }
  }
}

// ---------------- plain GEMM: out[r][col_off + 0:N] = A[r] @ W^T ----------------
template<int MT, int N, typename AT, typename OT>
__global__ __launch_bounds__(256) void plain_mfma(
    const AT* __restrict__ A, const float* __restrict__ W,
    OT* __restrict__ out, int K, int ldc, int col_off)
{
  constexpr int NTW    = N / 64;            // n-tiles per wave
  constexpr int NTILES = N / 16;
  __shared__ bf16x8 Alds[MT * 4 * 16];
  __shared__ bf16x8 Blds[NTILES * 4 * 16];

  const int tid  = threadIdx.x;
  const int lane = tid & 63;
  const int wv   = tid >> 6;
  const int quad = lane >> 4;
  const int lrow = lane & 15;
  const long r0  = (long)blockIdx.x * (MT * 16);

  f32x4 acc[MT][NTW];
#pragma unroll
  for (int mt = 0; mt < MT; ++mt)
#pragma unroll
    for (int nl = 0; nl < NTW; ++nl) acc[mt][nl] = (f32x4){0.f, 0.f, 0.f, 0.f};

  for (int kt = 0; kt < K; kt += 32) {
    __syncthreads();
    for (int i = tid; i < N * 4; i += 256) {
      const int n = i >> 2, kg = i & 3;
      Blds[((n >> 4) * 4 + kg) * 16 + (n & 15)] =
          load8_cvt(W + (long)n * K + kt + kg * 8);
    }
    for (int i = tid; i < MT * 16 * 4; i += 256) {
      const int mr = i >> 2, kg = i & 3;
      Alds[((mr >> 4) * 4 + kg) * 16 + (mr & 15)] =
          load8_cvt(A + (r0 + mr) * (long)K + kt + kg * 8);
    }
    __syncthreads();

    bf16x8 bfr[NTW];
#pragma unroll
    for (int nl = 0; nl < NTW; ++nl)
      bfr[nl] = Blds[((wv * NTW + nl) * 4 + quad) * 16 + lrow];
#pragma unroll
    for (int mt = 0; mt < MT; ++mt) {
      const bf16x8 afr = Alds[(mt * 4 + quad) * 16 + lrow];
#pragma unroll
      for (int nl = 0; nl < NTW; ++nl)
        acc[mt][nl] = __builtin_amdgcn_mfma_f32_16x16x32_bf16(
            afr, bfr[nl], acc[mt][nl], 0, 0, 0);
    }
  }

#pragma unroll
  for (int mt = 0; mt < MT; ++mt)
#pragma unroll
    for (int nl = 0; nl < NTW; ++nl) {
      const f32x4 v = acc[mt][nl];
      const int col = col_off + (wv * NTW + nl) * 16 + lrow;
#pragma unroll
      for (int reg = 0; reg < 4; ++reg) {
        const long row = r0 + mt * 16 + quad * 4 + reg;
        out[row * (long)ldc + col] = (OT)v[reg];
      }
    }
}

extern "C" void kernel_launch(void* const* d_in, const int* in_sizes, int n_in,
                              void* d_out, int out_size, void* d_ws, size_t ws_size,
                              hipStream_t stream) {
  const float* h0    = (const float*)d_in[0];   // (1024, 1, 256)
  const float* h1    = (const float*)d_in[1];   // (1024, 10, 256)
  const float* h2    = (const float*)d_in[2];   // (1024, 250, 256)
  const float* mask0 = (const float*)d_in[3];   // 10240 child rows
  const float* mask1 = (const float*)d_in[4];   // 256000 child rows
  const float* Ws0   = (const float*)d_in[5];
  const float* Wn0   = (const float*)d_in[6];
  const float* Wp0   = (const float*)d_in[7];
  const float* Ws1   = (const float*)d_in[8];
  const float* Wn1   = (const float*)d_in[9];
  const float* Wp1   = (const float*)d_in[10];
  const float* Wout  = (const float*)d_in[11];
  float* out = (float*)d_out;                   // (1024, 128) f32

  bf16_t* ws = (bf16_t*)d_ws;
  bf16_t* pooled1  = ws;                           // 10240 x 256
  bf16_t* states1  = pooled1  + 10240L * 256;      // 10240 x 512
  bf16_t* pooled0  = states1  + 10240L * 512;      // 1024 x 256
  bf16_t* states0  = pooled0  + 1024L * 256;       // 1024 x 512
  bf16_t* pooled1b = states0  + 1024L * 512;       // 1024 x 256
  bf16_t* states0b = pooled1b + 1024L * 256;       // 1024 x 512

  const dim3 blk(256);

  // 1. pooled1 = pool25(relu(h2 @ Wn0^T) * mask1)   [dominant]
  hipLaunchKernelGGL((pool_mfma<25, 32, 4, float>), dim3(2560), blk, 0, stream,
                     h2, Wn0, mask1, pooled1, 256);
  // 2. pooled0 = pool10(relu(h1 @ Wn0^T) * mask0)
  hipLaunchKernelGGL((pool_mfma<10, 16, 8, float>), dim3(128), blk, 0, stream,
                     h1, Wn0, mask0, pooled0, 256);
  // 3. states1[:, 0:256] = h1 @ Ws0^T
  hipLaunchKernelGGL((plain_mfma<4, 256, float, bf16_t>), dim3(160), blk, 0, stream,
                     h1, Ws0, states1, 256, 512, 0);
  // 4. states1[:, 256:512] = pooled1 @ Wp0^T
  hipLaunchKernelGGL((plain_mfma<4, 256, bf16_t, bf16_t>), dim3(160), blk, 0, stream,
                     pooled1, Wp0, states1, 256, 512, 256);
  // 5. states0[:, 0:256] = h0 @ Ws0^T
  hipLaunchKernelGGL((plain_mfma<1, 256, float, bf16_t>), dim3(64), blk, 0, stream,
                     h0, Ws0, states0, 256, 512, 0);
  // 6. states0[:, 256:512] = pooled0 @ Wp0^T
  hipLaunchKernelGGL((plain_mfma<1, 256, bf16_t, bf16_t>), dim3(64), blk, 0, stream,
                     pooled0, Wp0, states0, 256, 512, 256);
  // 7. pooled1b = pool10(relu(states1 @ Wn1^T) * mask0), K=512
  hipLaunchKernelGGL((pool_mfma<10, 16, 8, bf16_t>), dim3(128), blk, 0, stream,
                     states1, Wn1, mask0, pooled1b, 512);
  // 8. states0b[:, 0:256] = states0 @ Ws1^T, K=512
  hipLaunchKernelGGL((plain_mfma<1, 256, bf16_t, bf16_t>), dim3(64), blk, 0, stream,
                     states0, Ws1, states0b, 512, 512, 0);
  // 9. states0b[:, 256:512] = pooled1b @ Wp1^T, K=256
  hipLaunchKernelGGL((plain_mfma<1, 256, bf16_t, bf16_t>), dim3(64), blk, 0, stream,
                     pooled1b, Wp1, states0b, 256, 512, 256);
  // 10. out = states0b @ Wout^T, K=512, N=128, f32 out
  hipLaunchKernelGGL((plain_mfma<1, 128, bf16_t, float>), dim3(64), blk, 0, stream,
                     states0b, Wout, out, 512, 128, 0);
}

// Round 4
// 586.071 us; speedup vs baseline: 4.5124x; 1.3436x over previous
//
#include <hip/hip_runtime.h>
#include <hip/hip_bf16.h>

// GraphSAGE fused pipeline, bf16-MFMA v2.
// Changes vs v1: (a) weights pre-converted to bf16 once; (b) LDS staging uses
// linear slot mapping (thread t -> slot t, consecutive 16B addrs, conflict-free);
// (c) register double-buffering: next k-tile is prefetched into registers during
// the MFMA phase, hiding global latency.
// MFMA 16x16x32_bf16 layouts (verified by R3 pass):
//   A-frag: lane holds A[m=lane&15][k=(lane>>4)*8+j]
//   B-frag: lane holds W[n=lane&15][k=(lane>>4)*8+j]   (C = A @ W^T)
//   C/D   : col=lane&15, row=(lane>>4)*4+reg
// LDS slot s (16B) = (tile*4 + kgroup)*16 + row.

typedef __bf16 bf16_t;
typedef bf16_t bf16x8 __attribute__((ext_vector_type(8)));
typedef float  f32x4  __attribute__((ext_vector_type(4)));

__device__ inline bf16x8 cvt8(const float4 a, const float4 b) {
  bf16x8 t;
  t[0]=(bf16_t)a.x; t[1]=(bf16_t)a.y; t[2]=(bf16_t)a.z; t[3]=(bf16_t)a.w;
  t[4]=(bf16_t)b.x; t[5]=(bf16_t)b.y; t[6]=(bf16_t)b.z; t[7]=(bf16_t)b.w;
  return t;
}

__global__ __launch_bounds__(256) void cvt_bf16(
    const float* __restrict__ s, bf16_t* __restrict__ d, int n) {
  const int i = (blockIdx.x * 256 + threadIdx.x) * 8;
  if (i < n) {
    const float4 a = *(const float4*)(s + i);
    const float4 b = *(const float4*)(s + i + 4);
    *(bf16x8*)(d + i) = cvt8(a, b);
  }
}

// register prefetch holder: f32 source converts on LDS-write, bf16 is a raw copy
template<typename AT> struct PreA {
  float4 lo, hi;
  __device__ void fetch(const AT* p) { lo = *(const float4*)p; hi = *(const float4*)(p + 4); }
  __device__ bf16x8 get() const { return cvt8(lo, hi); }
};
template<> struct PreA<bf16_t> {
  bf16x8 v;
  __device__ void fetch(const bf16_t* p) { v = *(const bf16x8*)p; }
  __device__ bf16x8 get() const { return v; }
};

// ---- pooled GEMM: out[p][0:256] = max_{s<S} relu(A[p*S+s] @ W^T) * mask ----
template<int S, int PR, int P, typename AT>
__global__ __launch_bounds__(256) void pool_mfma(
    const AT* __restrict__ A, const bf16_t* __restrict__ W,
    const float* __restrict__ mask, bf16_t* __restrict__ out, int K)
{
  constexpr int ROWS = P * PR;            // 128
  constexpr int PM   = ROWS / 16;         // 8 m-tiles
  constexpr int MTP  = PR / 16;
  constexpr int APT  = (ROWS * 4) / 256;  // A slots per thread (2)
  __shared__ bf16x8 Blds[1024];           // 16 KB  (N=256 x 32k)
  __shared__ bf16x8 Alds[ROWS * 4];       // 8 KB
  __shared__ float  mlds[P * PR];

  const int tid  = threadIdx.x;
  const int lane = tid & 63, wv = tid >> 6, quad = lane >> 4, lrow = lane & 15;
  const long p0 = (long)blockIdx.x * P;

  if (tid < P * S) mlds[(tid / S) * PR + (tid % S)] = mask[p0 * S + tid];

  // per-thread slot -> global pointers (slot = tid + j*256)
  const bf16_t* bptr[4];
#pragma unroll
  for (int j = 0; j < 4; ++j) {
    const int s = tid + j * 256;
    bptr[j] = W + (long)((s >> 6) * 16 + (s & 15)) * K + ((s >> 4) & 3) * 8;
  }
  const AT* aptr[APT];
#pragma unroll
  for (int j = 0; j < APT; ++j) {
    const int s  = tid + j * 256;
    const int mr = (s >> 6) * 16 + (s & 15);
    const int p = mr / PR, r = mr % PR;
    const long grow = (p0 + p) * (long)S + (r < S ? r : S - 1);  // clamp pads
    aptr[j] = A + grow * (long)K + ((s >> 4) & 3) * 8;
  }

  f32x4 acc[PM][4];
#pragma unroll
  for (int pm = 0; pm < PM; ++pm)
#pragma unroll
    for (int nl = 0; nl < 4; ++nl) acc[pm][nl] = (f32x4){0.f, 0.f, 0.f, 0.f};

  // prefetch tile kt=0
  bf16x8 bpre[4];
  PreA<AT> apre[APT];
#pragma unroll
  for (int j = 0; j < 4; ++j) bpre[j] = *(const bf16x8*)(bptr[j]);
#pragma unroll
  for (int j = 0; j < APT; ++j) apre[j].fetch(aptr[j]);

  for (int kt = 0; kt < K; kt += 32) {
    __syncthreads();                      // prev iter's LDS reads done
#pragma unroll
    for (int j = 0; j < 4; ++j) Blds[tid + j * 256] = bpre[j];
#pragma unroll
    for (int j = 0; j < APT; ++j) Alds[tid + j * 256] = apre[j].get();
    __syncthreads();
    if (kt + 32 < K) {                    // prefetch next tile (overlaps MFMA)
#pragma unroll
      for (int j = 0; j < 4; ++j) bpre[j] = *(const bf16x8*)(bptr[j] + kt + 32);
#pragma unroll
      for (int j = 0; j < APT; ++j) apre[j].fetch(aptr[j] + kt + 32);
    }
    bf16x8 bfr[4];
#pragma unroll
    for (int nl = 0; nl < 4; ++nl)
      bfr[nl] = Blds[((wv * 4 + nl) * 4 + quad) * 16 + lrow];
#pragma unroll
    for (int pm = 0; pm < PM; ++pm) {
      const bf16x8 afr = Alds[(pm * 4 + quad) * 16 + lrow];
#pragma unroll
      for (int nl = 0; nl < 4; ++nl)
        acc[pm][nl] = __builtin_amdgcn_mfma_f32_16x16x32_bf16(
            afr, bfr[nl], acc[pm][nl], 0, 0, 0);
    }
  }

  // epilogue: relu -> *mask -> max over S rows per parent
#pragma unroll
  for (int p = 0; p < P; ++p) {
#pragma unroll
    for (int nl = 0; nl < 4; ++nl) {
      float m = 0.f;
#pragma unroll
      for (int mt = 0; mt < MTP; ++mt) {
        const f32x4 v = acc[p * MTP + mt][nl];
#pragma unroll
        for (int reg = 0; reg < 4; ++reg) {
          const int row = mt * 16 + quad * 4 + reg;
          if (row < S)
            m = fmaxf(m, fmaxf(v[reg], 0.f) * mlds[p * PR + row]);
        }
      }
      m = fmaxf(m, __shfl_xor(m, 16));
      m = fmaxf(m, __shfl_xor(m, 32));
      if (lane < 16)
        out[(p0 + p) * 256 + wv * 64 + nl * 16 + lrow] = (bf16_t)m;
    }
  }
}

// ---- plain GEMM: out[r][col_off + 0:N] = A[r] @ W^T ----
template<int MT, int N, typename AT, typename OT>
__global__ __launch_bounds__(256) void plain_mfma(
    const AT* __restrict__ A, const bf16_t* __restrict__ W,
    OT* __restrict__ out, int K, int ldc, int col_off)
{
  constexpr int NTW    = N / 64;
  constexpr int BSLOTS = N * 4;
  constexpr int BPT    = BSLOTS / 256;
  constexpr int ASLOTS = MT * 64;
  __shared__ bf16x8 Blds[BSLOTS];
  __shared__ bf16x8 Alds[ASLOTS];

  const int tid  = threadIdx.x;
  const int lane = tid & 63, wv = tid >> 6, quad = lane >> 4, lrow = lane & 15;
  const long r0 = (long)blockIdx.x * (MT * 16);

  const bf16_t* bptr[BPT];
#pragma unroll
  for (int j = 0; j < BPT; ++j) {
    const int s = tid + j * 256;
    bptr[j] = W + (long)((s >> 6) * 16 + (s & 15)) * K + ((s >> 4) & 3) * 8;
  }
  const bool aact = tid < ASLOTS;
  const AT* aptr = A;
  if (aact) {
    const int mr = (tid >> 6) * 16 + (tid & 15);
    aptr = A + (r0 + mr) * (long)K + ((tid >> 4) & 3) * 8;
  }

  f32x4 acc[MT][NTW];
#pragma unroll
  for (int mt = 0; mt < MT; ++mt)
#pragma unroll
    for (int nl = 0; nl < NTW; ++nl) acc[mt][nl] = (f32x4){0.f, 0.f, 0.f, 0.f};

  bf16x8 bpre[BPT];
  PreA<AT> apre;
#pragma unroll
  for (int j = 0; j < BPT; ++j) bpre[j] = *(const bf16x8*)(bptr[j]);
  if (aact) apre.fetch(aptr);

  for (int kt = 0; kt < K; kt += 32) {
    __syncthreads();
#pragma unroll
    for (int j = 0; j < BPT; ++j) Blds[tid + j * 256] = bpre[j];
    if (aact) Alds[tid] = apre.get();
    __syncthreads();
    if (kt + 32 < K) {
#pragma unroll
      for (int j = 0; j < BPT; ++j) bpre[j] = *(const bf16x8*)(bptr[j] + kt + 32);
      if (aact) apre.fetch(aptr + kt + 32);
    }
    bf16x8 bfr[NTW];
#pragma unroll
    for (int nl = 0; nl < NTW; ++nl)
      bfr[nl] = Blds[((wv * NTW + nl) * 4 + quad) * 16 + lrow];
#pragma unroll
    for (int mt = 0; mt < MT; ++mt) {
      const bf16x8 afr = Alds[(mt * 4 + quad) * 16 + lrow];
#pragma unroll
      for (int nl = 0; nl < NTW; ++nl)
        acc[mt][nl] = __builtin_amdgcn_mfma_f32_16x16x32_bf16(
            afr, bfr[nl], acc[mt][nl], 0, 0, 0);
    }
  }

#pragma unroll
  for (int mt = 0; mt < MT; ++mt)
#pragma unroll
    for (int nl = 0; nl < NTW; ++nl) {
      const f32x4 v = acc[mt][nl];
      const int col = col_off + (wv * NTW + nl) * 16 + lrow;
#pragma unroll
      for (int reg = 0; reg < 4; ++reg) {
        const long row = r0 + mt * 16 + quad * 4 + reg;
        out[row * (long)ldc + col] = (OT)v[reg];
      }
    }
}

extern "C" void kernel_launch(void* const* d_in, const int* in_sizes, int n_in,
                              void* d_out, int out_size, void* d_ws, size_t ws_size,
                              hipStream_t stream) {
  const float* h0    = (const float*)d_in[0];
  const float* h1    = (const float*)d_in[1];
  const float* h2    = (const float*)d_in[2];
  const float* mask0 = (const float*)d_in[3];
  const float* mask1 = (const float*)d_in[4];
  const float* Wf[7] = { (const float*)d_in[5], (const float*)d_in[6],
                         (const float*)d_in[7], (const float*)d_in[8],
                         (const float*)d_in[9], (const float*)d_in[10],
                         (const float*)d_in[11] };
  const int   Wn[7]  = { 65536, 65536, 65536, 131072, 131072, 65536, 65536 };
  float* out = (float*)d_out;

  bf16_t* ws = (bf16_t*)d_ws;
  bf16_t* Wb[7];
  {
    bf16_t* p = ws;
    for (int i = 0; i < 7; ++i) { Wb[i] = p; p += Wn[i]; }
  }
  bf16_t* base = ws + 589824;
  bf16_t* pooled1  = base;                         // 10240 x 256
  bf16_t* states1  = pooled1  + 10240L * 256;      // 10240 x 512
  bf16_t* pooled0  = states1  + 10240L * 512;      // 1024 x 256
  bf16_t* states0  = pooled0  + 1024L * 256;       // 1024 x 512
  bf16_t* pooled1b = states0  + 1024L * 512;       // 1024 x 256
  bf16_t* states0b = pooled1b + 1024L * 256;       // 1024 x 512

  const bf16_t *Ws0 = Wb[0], *Wn0 = Wb[1], *Wp0 = Wb[2], *Ws1 = Wb[3],
               *Wn1 = Wb[4], *Wp1 = Wb[5], *Wout = Wb[6];

  const dim3 blk(256);

  // 0. weights f32 -> bf16 (once per call)
  for (int i = 0; i < 7; ++i)
    hipLaunchKernelGGL(cvt_bf16, dim3(Wn[i] / 2048), blk, 0, stream,
                       Wf[i], Wb[i], Wn[i]);

  // 1. pooled1 = pool25(relu(h2 @ Wn0^T) * mask1)   [dominant]
  hipLaunchKernelGGL((pool_mfma<25, 32, 4, float>), dim3(2560), blk, 0, stream,
                     h2, Wn0, mask1, pooled1, 256);
  // 2. pooled0 = pool10(relu(h1 @ Wn0^T) * mask0)
  hipLaunchKernelGGL((pool_mfma<10, 16, 8, float>), dim3(128), blk, 0, stream,
                     h1, Wn0, mask0, pooled0, 256);
  // 3. states1[:, 0:256] = h1 @ Ws0^T
  hipLaunchKernelGGL((plain_mfma<4, 256, float, bf16_t>), dim3(160), blk, 0, stream,
                     h1, Ws0, states1, 256, 512, 0);
  // 4. states1[:, 256:512] = pooled1 @ Wp0^T
  hipLaunchKernelGGL((plain_mfma<4, 256, bf16_t, bf16_t>), dim3(160), blk, 0, stream,
                     pooled1, Wp0, states1, 256, 512, 256);
  // 5. states0[:, 0:256] = h0 @ Ws0^T
  hipLaunchKernelGGL((plain_mfma<1, 256, float, bf16_t>), dim3(64), blk, 0, stream,
                     h0, Ws0, states0, 256, 512, 0);
  // 6. states0[:, 256:512] = pooled0 @ Wp0^T
  hipLaunchKernelGGL((plain_mfma<1, 256, bf16_t, bf16_t>), dim3(64), blk, 0, stream,
                     pooled0, Wp0, states0, 256, 512, 256);
  // 7. pooled1b = pool10(relu(states1 @ Wn1^T) * mask0), K=512
  hipLaunchKernelGGL((pool_mfma<10, 16, 8, bf16_t>), dim3(128), blk, 0, stream,
                     states1, Wn1, mask0, pooled1b, 512);
  // 8. states0b[:, 0:256] = states0 @ Ws1^T, K=512
  hipLaunchKernelGGL((plain_mfma<1, 256, bf16_t, bf16_t>), dim3(64), blk, 0, stream,
                     states0, Ws1, states0b, 512, 512, 0);
  // 9. states0b[:, 256:512] = pooled1b @ Wp1^T, K=256
  hipLaunchKernelGGL((plain_mfma<1, 256, bf16_t, bf16_t>), dim3(64), blk, 0, stream,
                     pooled1b, Wp1, states0b, 256, 512, 256);
  // 10. out = states0b @ Wout^T, K=512, N=128, f32 out
  hipLaunchKernelGGL((plain_mfma<1, 128, bf16_t, float>), dim3(64), blk, 0, stream,
                     states0b, Wout, out, 512, 128, 0);
}

// Round 5
// 539.393 us; speedup vs baseline: 4.9029x; 1.0865x over previous
//
#include <hip/hip_runtime.h>

// GraphSAGE fused pipeline, bf16-MFMA v3.
// vs v2: (a) 64-row M-tiles (acc=64 regs) -> ~3 blocks/CU instead of 1;
// (b) W staged via async global_load_lds (width 16, wave-uniform base, slot
// map = lane-linear); (c) double-buffered LDS, ONE barrier per k-iter;
// (d) 2-deep A register prefetch (fetch tile i+3, consume at iter i+2);
// (e) h0/h1 pre-converted to bf16; op3+4 and op5+6 merged via gridDim.y.
// MFMA 16x16x32_bf16 layouts (verified R3/R4 pass):
//   A-frag: lane holds A[m=lane&15][k=(lane>>4)*8+j]
//   B-frag: lane holds W[n=lane&15][k=(lane>>4)*8+j]   (C = A @ W^T)
//   C/D   : col=lane&15, row=(lane>>4)*4+reg
// LDS slot s (16B) = ((row>>4)*4 + kgroup)*16 + (row&15); staging thread t
// writes slot t + j*256 (consecutive 16B -> conflict-free).

typedef __bf16 bf16_t;
typedef bf16_t bf16x8 __attribute__((ext_vector_type(8)));
typedef float  f32x4  __attribute__((ext_vector_type(4)));

__device__ inline bf16x8 cvt8(const float4 a, const float4 b) {
  bf16x8 t;
  t[0]=(bf16_t)a.x; t[1]=(bf16_t)a.y; t[2]=(bf16_t)a.z; t[3]=(bf16_t)a.w;
  t[4]=(bf16_t)b.x; t[5]=(bf16_t)b.y; t[6]=(bf16_t)b.z; t[7]=(bf16_t)b.w;
  return t;
}

__global__ __launch_bounds__(256) void cvt_bf16(
    const float* __restrict__ s, bf16_t* __restrict__ d, int n) {
  const int i = (blockIdx.x * 256 + threadIdx.x) * 8;
  if (i < n) {
    const float4 a = *(const float4*)(s + i);
    const float4 b = *(const float4*)(s + i + 4);
    *(bf16x8*)(d + i) = cvt8(a, b);
  }
}

// async global->LDS, 16B per lane; lds dest must be wave-uniform base
__device__ inline void gload_lds16(const bf16_t* g, bf16x8* l) {
  __builtin_amdgcn_global_load_lds(
      (const __attribute__((address_space(1))) unsigned int*)g,
      (__attribute__((address_space(3))) unsigned int*)l, 16, 0, 0);
}

template<typename AT> struct PreA {            // f32 source: cvt on LDS-write
  float4 lo, hi;
  __device__ void fetch(const AT* p) { lo = *(const float4*)p; hi = *(const float4*)(p + 4); }
  __device__ bf16x8 get() const { return cvt8(lo, hi); }
};
template<> struct PreA<bf16_t> {               // bf16 source: raw 16B
  bf16x8 v;
  __device__ void fetch(const bf16_t* p) { v = *(const bf16x8*)p; }
  __device__ bf16x8 get() const { return v; }
};

// ---- pooled GEMM: out[p][0:256] = max_{s<S} relu(A[p*S+s] @ W^T) * mask ----
template<int S, int PR, int P, int K, typename AT>
__global__ __launch_bounds__(256) void pool_mfma(
    const AT* __restrict__ A, const bf16_t* __restrict__ W,
    const float* __restrict__ mask, bf16_t* __restrict__ out)
{
  constexpr int ROWS = P * PR;                 // 64
  constexpr int PM   = ROWS / 16;              // 4
  constexpr int MTP  = PR / 16;
  constexpr int T    = K / 32;
  __shared__ bf16x8 Blds[2][1024];             // 32 KB (N=256)
  __shared__ bf16x8 Alds[2][ROWS * 4];         // 8 KB
  __shared__ float  mlds[ROWS];

  const int tid  = threadIdx.x;
  const int lane = tid & 63, wv = tid >> 6, quad = lane >> 4, lrow = lane & 15;
  const long p0  = (long)blockIdx.x * P;

  if (tid < P * S) mlds[(tid / S) * PR + (tid % S)] = mask[p0 * S + tid];

  const bf16_t* wptr[4];
#pragma unroll
  for (int j = 0; j < 4; ++j) {
    const int n = ((tid >> 6) + j * 4) * 16 + (tid & 15);
    wptr[j] = W + (long)n * K + ((tid >> 4) & 3) * 8;
  }
  const int wbase = (tid >> 6) * 64;           // wave-uniform LDS slot base

  const int mr = (tid >> 6) * 16 + (tid & 15);
  const int pp = mr / PR, rr = mr % PR;
  const long grow = (p0 + pp) * (long)S + (rr < S ? rr : S - 1);  // clamp pads
  const AT* aptr = A + grow * (long)K + ((tid >> 4) & 3) * 8;

  f32x4 acc[PM][4];
#pragma unroll
  for (int pm = 0; pm < PM; ++pm)
#pragma unroll
    for (int nl = 0; nl < 4; ++nl) acc[pm][nl] = (f32x4){0.f, 0.f, 0.f, 0.f};

  // prologue: tile0 -> buf0; apre[0]=tile1, apre[1]=tile2 (T>=8 always)
  PreA<AT> a0, apre[2];
  a0.fetch(aptr);
#pragma unroll
  for (int j = 0; j < 4; ++j) gload_lds16(wptr[j], &Blds[0][wbase + j * 256]);
  apre[0].fetch(aptr + 32);
  apre[1].fetch(aptr + 64);
  Alds[0][tid] = a0.get();
  __syncthreads();                             // drains async W too

#pragma unroll
  for (int i = 0; i < T; ++i) {
    const int cur = i & 1, nxt = cur ^ 1;
    if (i + 1 < T) {                           // async W tile i+1 -> other buf
#pragma unroll
      for (int j = 0; j < 4; ++j)
        gload_lds16(wptr[j] + (i + 1) * 32, &Blds[nxt][wbase + j * 256]);
    }
    bf16x8 bfr[4];
#pragma unroll
    for (int nl = 0; nl < 4; ++nl)
      bfr[nl] = Blds[cur][((wv * 4 + nl) * 4 + quad) * 16 + lrow];
#pragma unroll
    for (int pm = 0; pm < PM; ++pm) {
      const bf16x8 afr = Alds[cur][(pm * 4 + quad) * 16 + lrow];
#pragma unroll
      for (int nl = 0; nl < 4; ++nl)
        acc[pm][nl] = __builtin_amdgcn_mfma_f32_16x16x32_bf16(
            afr, bfr[nl], acc[pm][nl], 0, 0, 0);
    }
    if (i + 1 < T) {
      Alds[nxt][tid] = apre[i & 1].get();      // consume tile i+1
      if (i + 3 < T) apre[i & 1].fetch(aptr + (i + 3) * 32);  // fetch tile i+3
      __syncthreads();
    }
  }

  // epilogue: relu -> *mask -> max over S rows per parent
#pragma unroll
  for (int p = 0; p < P; ++p) {
#pragma unroll
    for (int nl = 0; nl < 4; ++nl) {
      float m = 0.f;
#pragma unroll
      for (int mt = 0; mt < MTP; ++mt) {
        const f32x4 v = acc[p * MTP + mt][nl];
#pragma unroll
        for (int reg = 0; reg < 4; ++reg) {
          const int row = mt * 16 + quad * 4 + reg;
          if (row < S)
            m = fmaxf(m, fmaxf(v[reg], 0.f) * mlds[p * PR + row]);
        }
      }
      m = fmaxf(m, __shfl_xor(m, 16));
      m = fmaxf(m, __shfl_xor(m, 32));
      if (lane < 16)
        out[(p0 + p) * 256 + wv * 64 + nl * 16 + lrow] = (bf16_t)m;
    }
  }
}

// ---- plain GEMM: out[r][coff + 0:N] = A[r] @ W^T ; (A,W,coff) by blockIdx.y ----
template<int MT, int N, int K, typename OT>
__global__ __launch_bounds__(256) void plain_mfma(
    const bf16_t* __restrict__ A0, const bf16_t* __restrict__ W0, int c0,
    const bf16_t* __restrict__ A1, const bf16_t* __restrict__ W1, int c1,
    OT* __restrict__ out, int ldc)
{
  constexpr int NTW    = N / 64;
  constexpr int BSLOTS = N * 4;
  constexpr int BPT    = BSLOTS / 256;
  constexpr int ROWS   = MT * 16;
  constexpr int ASLOTS = ROWS * 4;
  constexpr int T      = K / 32;
  __shared__ bf16x8 Blds[2][BSLOTS];
  __shared__ bf16x8 Alds[2][ASLOTS];

  const bf16_t* __restrict__ A = blockIdx.y ? A1 : A0;
  const bf16_t* __restrict__ W = blockIdx.y ? W1 : W0;
  const int coff = blockIdx.y ? c1 : c0;

  const int tid  = threadIdx.x;
  const int lane = tid & 63, wv = tid >> 6, quad = lane >> 4, lrow = lane & 15;
  const long r0  = (long)blockIdx.x * ROWS;

  const bf16_t* wptr[BPT];
#pragma unroll
  for (int j = 0; j < BPT; ++j) {
    const int n = ((tid >> 6) + j * 4) * 16 + (tid & 15);
    wptr[j] = W + (long)n * K + ((tid >> 4) & 3) * 8;
  }
  const int wbase = (tid >> 6) * 64;

  const bool aact = tid < ASLOTS;
  const int  mr   = (tid >> 6) * 16 + (tid & 15);
  const bf16_t* aptr = A + (aact ? (r0 + mr) * (long)K + ((tid >> 4) & 3) * 8 : 0);

  f32x4 acc[MT][NTW];
#pragma unroll
  for (int mt = 0; mt < MT; ++mt)
#pragma unroll
    for (int nl = 0; nl < NTW; ++nl) acc[mt][nl] = (f32x4){0.f, 0.f, 0.f, 0.f};

  PreA<bf16_t> a0p, apre[2];
  if (aact) a0p.fetch(aptr);
#pragma unroll
  for (int j = 0; j < BPT; ++j) gload_lds16(wptr[j], &Blds[0][wbase + j * 256]);
  if (aact) {
    apre[0].fetch(aptr + 32);
    apre[1].fetch(aptr + 64);
    Alds[0][tid] = a0p.get();
  }
  __syncthreads();

#pragma unroll
  for (int i = 0; i < T; ++i) {
    const int cur = i & 1, nxt = cur ^ 1;
    if (i + 1 < T) {
#pragma unroll
      for (int j = 0; j < BPT; ++j)
        gload_lds16(wptr[j] + (i + 1) * 32, &Blds[nxt][wbase + j * 256]);
    }
    bf16x8 bfr[NTW];
#pragma unroll
    for (int nl = 0; nl < NTW; ++nl)
      bfr[nl] = Blds[cur][((wv * NTW + nl) * 4 + quad) * 16 + lrow];
#pragma unroll
    for (int mt = 0; mt < MT; ++mt) {
      const bf16x8 afr = Alds[cur][(mt * 4 + quad) * 16 + lrow];
#pragma unroll
      for (int nl = 0; nl < NTW; ++nl)
        acc[mt][nl] = __builtin_amdgcn_mfma_f32_16x16x32_bf16(
            afr, bfr[nl], acc[mt][nl], 0, 0, 0);
    }
    if (i + 1 < T) {
      if (aact) {
        Alds[nxt][tid] = apre[i & 1].get();
        if (i + 3 < T) apre[i & 1].fetch(aptr + (i + 3) * 32);
      }
      __syncthreads();
    }
  }

#pragma unroll
  for (int mt = 0; mt < MT; ++mt)
#pragma unroll
    for (int nl = 0; nl < NTW; ++nl) {
      const f32x4 v = acc[mt][nl];
      const int col = coff + (wv * NTW + nl) * 16 + lrow;
#pragma unroll
      for (int reg = 0; reg < 4; ++reg) {
        const long row = r0 + mt * 16 + quad * 4 + reg;
        out[row * (long)ldc + col] = (OT)v[reg];
      }
    }
}

extern "C" void kernel_launch(void* const* d_in, const int* in_sizes, int n_in,
                              void* d_out, int out_size, void* d_ws, size_t ws_size,
                              hipStream_t stream) {
  const float* h0f   = (const float*)d_in[0];
  const float* h1f   = (const float*)d_in[1];
  const float* h2    = (const float*)d_in[2];
  const float* mask0 = (const float*)d_in[3];
  const float* mask1 = (const float*)d_in[4];
  const float* Wf[7] = { (const float*)d_in[5], (const float*)d_in[6],
                         (const float*)d_in[7], (const float*)d_in[8],
                         (const float*)d_in[9], (const float*)d_in[10],
                         (const float*)d_in[11] };
  const int   Wn[7]  = { 65536, 65536, 65536, 131072, 131072, 65536, 65536 };
  float* out = (float*)d_out;

  bf16_t* p = (bf16_t*)d_ws;
  bf16_t* Wb[7];
  for (int i = 0; i < 7; ++i) { Wb[i] = p; p += Wn[i]; }
  bf16_t* h0b = p;      p += 262144;               // 1024 x 256
  bf16_t* h1b = p;      p += 2621440;              // 10240 x 256
  bf16_t* pooled1  = p; p += 10240L * 256;
  bf16_t* states1  = p; p += 10240L * 512;
  bf16_t* pooled0  = p; p += 1024L * 256;
  bf16_t* states0  = p; p += 1024L * 512;
  bf16_t* pooled1b = p; p += 1024L * 256;
  bf16_t* states0b = p; p += 1024L * 512;

  const bf16_t *Ws0 = Wb[0], *Wn0 = Wb[1], *Wp0 = Wb[2], *Ws1 = Wb[3],
               *Wn1 = Wb[4], *Wp1 = Wb[5], *Wout = Wb[6];
  const dim3 blk(256);

  // 0. f32 -> bf16 conversions (weights + h0 + h1)
  for (int i = 0; i < 7; ++i)
    hipLaunchKernelGGL(cvt_bf16, dim3(Wn[i] / 2048), blk, 0, stream, Wf[i], Wb[i], Wn[i]);
  hipLaunchKernelGGL(cvt_bf16, dim3(128),  blk, 0, stream, h0f, h0b, 262144);
  hipLaunchKernelGGL(cvt_bf16, dim3(1280), blk, 0, stream, h1f, h1b, 2621440);

  // 1. pooled1 = pool25(relu(h2 @ Wn0^T) * mask1)   [dominant, A stays f32]
  hipLaunchKernelGGL((pool_mfma<25, 32, 2, 256, float>), dim3(5120), blk, 0, stream,
                     h2, Wn0, mask1, pooled1);
  // 2. pooled0 = pool10(relu(h1 @ Wn0^T) * mask0)
  hipLaunchKernelGGL((pool_mfma<10, 16, 4, 256, bf16_t>), dim3(256), blk, 0, stream,
                     h1b, Wn0, mask0, pooled0);
  // 3+4. states1 = [h1 @ Ws0^T | pooled1 @ Wp0^T]
  hipLaunchKernelGGL((plain_mfma<4, 256, 256, bf16_t>), dim3(160, 2), blk, 0, stream,
                     h1b, Ws0, 0, pooled1, Wp0, 256, states1, 512);
  // 5+6. states0 = [h0 @ Ws0^T | pooled0 @ Wp0^T]
  hipLaunchKernelGGL((plain_mfma<1, 256, 256, bf16_t>), dim3(64, 2), blk, 0, stream,
                     h0b, Ws0, 0, pooled0, Wp0, 256, states0, 512);
  // 7. pooled1b = pool10(relu(states1 @ Wn1^T) * mask0), K=512
  hipLaunchKernelGGL((pool_mfma<10, 16, 4, 512, bf16_t>), dim3(256), blk, 0, stream,
                     states1, Wn1, mask0, pooled1b);
  // 8. states0b[:, 0:256] = states0 @ Ws1^T, K=512
  hipLaunchKernelGGL((plain_mfma<1, 256, 512, bf16_t>), dim3(64, 1), blk, 0, stream,
                     states0, Ws1, 0, states0, Ws1, 0, states0b, 512);
  // 9. states0b[:, 256:512] = pooled1b @ Wp1^T, K=256
  hipLaunchKernelGGL((plain_mfma<1, 256, 256, bf16_t>), dim3(64, 1), blk, 0, stream,
                     pooled1b, Wp1, 256, pooled1b, Wp1, 256, states0b, 512);
  // 10. out = states0b @ Wout^T, K=512, N=128, f32 out
  hipLaunchKernelGGL((plain_mfma<1, 128, 512, float>), dim3(64, 1), blk, 0, stream,
                     states0b, Wout, 0, states0b, Wout, 0, out, 128);
}